// Round 9
// baseline (126.908 us; speedup 1.0000x reference)
//
#include <hip/hip_runtime.h>

// SimpleCRFHead R14: R13 (full-wave quad-split, branch-free bodies, batched
// path-score; crf_half ~37.5us) + window-level software pipeline:
//   - 3-slot LDS ring, prefetch depth 2, counted s_waitcnt vmcnt(16)
//   - each loop iteration reads {e, em, tr, p} for window b+1 and runs the
//     6 serial chains for window b in ONE basic block -> scheduler hides
//     the ds_read/v_exp phase under the DPP/FMA dependency chains.
//   - prologue ends with vmcnt(0) drain so compiler-tracked prologue loads
//     (Erot/ltran/pl255) never skew the in-loop counted vmcnt.
// Math bit-identical to R13 (absmax 0.0): same ops, same order; reads are
// merely issued one window earlier.

#define B_N 8192
#define L_N 256
#define SEQ_STRIDE 2304      // L_N * 9
#define HALF 128
#define SPB 6                // steps per x window
#define XW 54                // floats per seq per window
#define XSTRIDE 55           // odd -> conflict-free LDS banks
#define PLS 129              // path LDS row stride
#define SPW 16               // seqs per wave (full wave: 16 quads)
#define NDIR_BLOCKS (B_N / SPW)   // 512 per direction

#define LOG2E 1.44269504088896340736f
#define LN2f  0.69314718055994530942f

// quad_perm rotate-left-by-r: lane c receives quad-lane (c+r)&3
#define QP1 57    // perm(1,2,3,0)
#define QP2 78    // perm(2,3,0,1)
#define QP3 147   // perm(3,0,1,2)
#define QROT(src, CTRL) \
  __int_as_float(__builtin_amdgcn_mov_dpp(__float_as_int(src), CTRL, 0xf, 0xf, 0))

#define WAITV0  asm volatile("s_waitcnt vmcnt(0)" ::: "memory")
#define WAITV16 asm volatile("s_waitcnt vmcnt(16)" ::: "memory")

__device__ __forceinline__ void gl_lds4(const void* g, void* l) {
  __builtin_amdgcn_global_load_lds(
      (const __attribute__((address_space(1))) void*)g,
      (__attribute__((address_space(3))) void*)l, 4, 0, 0);
}

__device__ __forceinline__ float fexp(float x) {
  return __builtin_amdgcn_exp2f(x * LOG2E);   // v_exp_f32 = 2^x
}

// ---- straight-line step bodies (KK, EA, DO_RESC compile-time) ----
#define FWD_STEP_BODY(KK, EA, DO_RESC)                                      \
  do {                                                                      \
    float g[4][3];                                                          \
    _Pragma("unroll") for (int k = 0; k < 3; ++k) {                         \
      g[0][k] = o[k];                                                       \
      g[1][k] = QROT(o[k], QP1);                                            \
      g[2][k] = QROT(o[k], QP2);                                            \
      g[3][k] = QROT(o[k], QP3);                                            \
    }                                                                       \
    if (DO_RESC) {                                                          \
      float m = g[0][0];                                                    \
      _Pragma("unroll") for (int r = 0; r < 4; ++r)                         \
        _Pragma("unroll") for (int k = 0; k < 3; ++k)                       \
          m = fmaxf(m, g[r][k]);                                            \
      const int ex = (int)((__float_as_uint(m) >> 23) & 0xffu) - 126;       \
      ce += ex;                                                             \
      const float sc = __uint_as_float((unsigned)(127 - ex) << 23);         \
      _Pragma("unroll") for (int r = 0; r < 4; ++r)                         \
        _Pragma("unroll") for (int k = 0; k < 3; ++k)                       \
          g[r][k] *= sc;                                                    \
    }                                                                       \
    float out3[3];                                                          \
    _Pragma("unroll") for (int i = 0; i < 3; ++i) {                         \
      float a = Erot[0][0][i] * g[0][0];                                    \
      _Pragma("unroll") for (int r = 0; r < 4; ++r)                         \
        _Pragma("unroll") for (int k = 0; k < 3; ++k)                       \
          if (r + k > 0) a = fmaf(Erot[r][k][i], g[r][k], a);               \
      out3[i] = a;                                                          \
    }                                                                       \
    _Pragma("unroll") for (int i = 0; i < 3; ++i)                           \
      o[i] = out3[i] * EA[(KK) * 3 + i];                                    \
  } while (0)

#define BWD_STEP_BODY(KK, EA, DO_RESC)                                      \
  do {                                                                      \
    const int tt_ = 5 - (KK);                                               \
    float wv[3];                                                            \
    _Pragma("unroll") for (int k = 0; k < 3; ++k)                           \
      wv[k] = EA[tt_ * 3 + k] * o[k];                                       \
    float g[4][3];                                                          \
    _Pragma("unroll") for (int k = 0; k < 3; ++k) {                         \
      g[0][k] = wv[k];                                                      \
      g[1][k] = QROT(wv[k], QP1);                                           \
      g[2][k] = QROT(wv[k], QP2);                                           \
      g[3][k] = QROT(wv[k], QP3);                                           \
    }                                                                       \
    if (DO_RESC) {                                                          \
      float m = g[0][0];                                                    \
      _Pragma("unroll") for (int r = 0; r < 4; ++r)                         \
        _Pragma("unroll") for (int k = 0; k < 3; ++k)                       \
          m = fmaxf(m, g[r][k]);                                            \
      const int ex = (int)((__float_as_uint(m) >> 23) & 0xffu) - 126;       \
      ce += ex;                                                             \
      const float sc = __uint_as_float((unsigned)(127 - ex) << 23);         \
      _Pragma("unroll") for (int r = 0; r < 4; ++r)                         \
        _Pragma("unroll") for (int k = 0; k < 3; ++k)                       \
          g[r][k] *= sc;                                                    \
    }                                                                       \
    float out3[3];                                                          \
    _Pragma("unroll") for (int i = 0; i < 3; ++i) {                         \
      float a = Erot[0][0][i] * g[0][0];                                    \
      _Pragma("unroll") for (int r = 0; r < 4; ++r)                         \
        _Pragma("unroll") for (int k = 0; k < 3; ++k)                       \
          if (r + k > 0) a = fmaf(Erot[r][k][i], g[r][k], a);               \
      out3[i] = a;                                                          \
    }                                                                       \
    _Pragma("unroll") for (int i = 0; i < 3; ++i) o[i] = out3[i];           \
  } while (0)

#define PREFETCH_WIN(NB)                                                    \
  if (lane < XW) {                                                          \
    const int fb = fwd ? (NB) * XW : (SEQ_STRIDE - XW * ((NB) + 1));        \
    float* dst = &lx[(NB) % 3][0];                                          \
    _Pragma("unroll") for (int r = 0; r < SPW; ++r)                         \
      gl_lds4(xg + (size_t)(seq0 + r) * SEQ_STRIDE + fb + lane,             \
              dst + r * XSTRIDE);                                           \
  }

#define EBATCH_TO(EA, LXQ)                                                  \
  _Pragma("unroll") for (int tt = 0; tt < 6; ++tt)                          \
    _Pragma("unroll") for (int k = 0; k < 3; ++k)                           \
      EA[tt * 3 + k] = fexp((LXQ)[tt * 9 + myoff + k]);

#define EMTR_FWD_TO(EMA, TRA, LXQ, PCA, PPREV)                              \
  _Pragma("unroll") for (int kk = 0; kk < 6; ++kk) {                        \
    EMA[kk] = (LXQ)[kk * 9 + PCA[kk]];                                      \
    const int pp_ = kk ? PCA[kk - 1] : (PPREV);                             \
    TRA[kk] = ltran[pp_ * 9 + PCA[kk]];                                     \
  }

#define EMTR_BWD_TO(EMA, TRA, LXQ, PCA, PPREV)                              \
  _Pragma("unroll") for (int kk = 0; kk < 6; ++kk) {                        \
    const int pc_ = kk ? PCA[kk - 1] : (PPREV);                             \
    EMA[kk] = (LXQ)[(5 - kk) * 9 + pc_];                                    \
    TRA[kk] = ltran[PCA[kk] * 9 + pc_];                                     \
  }

#define PREREAD_TO(PNA, TBN)                                                \
  if (fwd) {                                                                \
    _Pragma("unroll") for (int kk = 0; kk < 6; ++kk) {                      \
      int t_ = (TBN) + kk; if (t_ > HALF - 1) t_ = HALF - 1;                \
      PNA[kk] = plr[t_];                                                    \
    }                                                                       \
  } else {                                                                  \
    _Pragma("unroll") for (int kk = 0; kk < 6; ++kk) {                      \
      int idx_ = 127 - (TBN) - kk; if (idx_ < 0) idx_ = 0;                  \
      PNA[kk] = plr[idx_];                                                  \
    }                                                                       \
  }

#define ROTATE_NEXT                                                         \
  _Pragma("unroll") for (int j = 0; j < 18; ++j) eC[j] = eN[j];             \
  _Pragma("unroll") for (int j = 0; j < 6; ++j) {                           \
    emC[j] = emN[j]; trC[j] = trN[j]; pcC[j] = pcN[j]; pcN[j] = pnN[j];     \
  }

__global__ __launch_bounds__(64, 1) void crf_half(
    const float* __restrict__ xg, const int* __restrict__ path,
    const float* __restrict__ tran, const float* __restrict__ initv,
    float* __restrict__ ws)
{
  __shared__ float lx[3][SPW * XSTRIDE];  // 10560 B (3-slot ring)
  __shared__ int   pl[SPW * PLS];         // 8256 B
  __shared__ int   pl255[SPW];
  __shared__ float ltran[81];             // ~19.2 KB

  const int lane = threadIdx.x;
  const int c = lane & 3;                 // quad slot (state group)
  const int q = lane >> 2;                // seq slot (0..15)
  const bool fwd = (int)blockIdx.x < NDIR_BLOCKS;
  const int seq0 = (fwd ? blockIdx.x : blockIdx.x - NDIR_BLOCKS) * SPW;

  for (int i = lane; i < 81; i += 64) ltran[i] = tran[i];
  if (!fwd && lane < SPW)
    pl255[lane] = path[(size_t)(seq0 + lane) * L_N + 255];

  // ---- stage path rows + x windows 0,1 (coalesced gl_lds)
  {
    const int t0 = fwd ? 0 : 127;
#pragma unroll
    for (int r = 0; r < SPW; ++r) {
      const int* g = path + (size_t)(seq0 + r) * L_N + t0 + lane;
      gl_lds4(g,      &pl[r * PLS]);
      gl_lds4(g + 64, &pl[r * PLS + 64]);
    }
  }
  if (lane < XW) {
#pragma unroll
    for (int wi = 0; wi < 2; ++wi) {
      const int fb = fwd ? wi * XW : (SEQ_STRIDE - XW * (wi + 1));
#pragma unroll
      for (int r = 0; r < SPW; ++r)
        gl_lds4(xg + (size_t)(seq0 + r) * SEQ_STRIDE + fb + lane,
                &lx[wi][r * XSTRIDE]);
    }
  }

  // ---- rotation-ordered transition coefficients (prologue only)
  float Erot[4][3][3];
#pragma unroll
  for (int r = 0; r < 4; ++r)
#pragma unroll
    for (int k = 0; k < 3; ++k)
#pragma unroll
      for (int i = 0; i < 3; ++i) {
        const int ig = 3 * c + i;
        const int jg = 3 * ((c + r) & 3) + k;
        float v = 0.f;
        if (ig < 9 && jg < 9)
          v = fexp(fwd ? tran[jg * 9 + ig] : tran[ig * 9 + jg]);
        Erot[r][k][i] = v;
      }

  float iv[3];
#pragma unroll
  for (int k = 0; k < 3; ++k) {
    iv[k] = (fwd && c < 3) ? initv[3 * c + k] : 0.f;
    asm volatile("" :: "v"(iv[k]));       // pin materialization to prologue
  }

  float o[3];
  float emit = 0.f, trn = 0.f;
  int ce = 0, pcur = 0;
  if (!fwd) {
#pragma unroll
    for (int k = 0; k < 3; ++k) o[k] = (c < 3) ? 1.f : 0.f;
  }

  const int myoff = (c == 3) ? 0 : 3 * c;
  const int* plr = &pl[q * PLS];

  WAITV0;                     // drain ALL prologue vmem (robust count base)
  if (!fwd) pcur = pl255[q];

  // ---- window-0 state: p, e, em, tr; window-1 p pre-read
  int pcC[6], pcN[6];
  if (fwd) {
#pragma unroll
    for (int kk = 0; kk < 6; ++kk) pcC[kk] = plr[kk];
  } else {
#pragma unroll
    for (int kk = 0; kk < 6; ++kk) pcC[kk] = plr[127 - kk];
  }
  float eC[18], emC[6], trC[6];
  {
    const float* lxq0 = &lx[0][q * XSTRIDE];
    EBATCH_TO(eC, lxq0)
    if (fwd) { EMTR_FWD_TO(emC, trC, lxq0, pcC, pcur) }
    else     { EMTR_BWD_TO(emC, trC, lxq0, pcC, pcur) }
  }
  float xv0[3];
#pragma unroll
  for (int k = 0; k < 3; ++k) xv0[k] = lx[0][q * XSTRIDE + myoff + k];
  PREREAD_TO(pcN, SPB)

  // ================= iteration b=0 (peeled: t==0 special, no rescale) ====
  {
    PREFETCH_WIN(2)
    WAITV16;                  // window 1 resident (window 2 in flight)
    const float* lxqN = &lx[1][q * XSTRIDE];
    float eN[18], emN[6], trN[6]; int pnN[6];
    EBATCH_TO(eN, lxqN)
    if (fwd) { EMTR_FWD_TO(emN, trN, lxqN, pcN, pcC[5]) }
    else     { EMTR_BWD_TO(emN, trN, lxqN, pcN, pcC[5]) }
    PREREAD_TO(pnN, 2 * SPB)
    if (fwd) {
#pragma unroll
      for (int k = 0; k < 3; ++k)
        o[k] = (c < 3) ? fexp(iv[k] + xv0[k]) : 0.f;
      FWD_STEP_BODY(1, eC, false);
      FWD_STEP_BODY(2, eC, false);
      FWD_STEP_BODY(3, eC, false);
      FWD_STEP_BODY(4, eC, false);
      FWD_STEP_BODY(5, eC, false);
#pragma unroll
      for (int kk = 0; kk < 6; ++kk) emit += emC[kk];
#pragma unroll
      for (int kk = 1; kk < 6; ++kk) trn += trC[kk];  // t==0: no transition
    } else {
      BWD_STEP_BODY(0, eC, false);
      BWD_STEP_BODY(1, eC, false);
      BWD_STEP_BODY(2, eC, false);
      BWD_STEP_BODY(3, eC, false);
      BWD_STEP_BODY(4, eC, false);
      BWD_STEP_BODY(5, eC, false);
#pragma unroll
      for (int kk = 0; kk < 6; ++kk) { emit += emC[kk]; trn += trC[kk]; }
    }
    ROTATE_NEXT
  }

  // ================= iterations b=1..20 (pipelined, branch-free) =========
#pragma unroll 1
  for (int b = 1; b <= 20; ++b) {
    if (b + 2 <= 21) {
      PREFETCH_WIN(b + 2)
      WAITV16;                // window b+1 resident (b+2 in flight)
    } else {
      WAITV0;                 // b==20: window 21 resident
    }
    const float* lxqN = &lx[(b + 1) % 3][q * XSTRIDE];
    float eN[18], emN[6], trN[6]; int pnN[6];
    EBATCH_TO(eN, lxqN)
    if (fwd) { EMTR_FWD_TO(emN, trN, lxqN, pcN, pcC[5]) }
    else     { EMTR_BWD_TO(emN, trN, lxqN, pcN, pcC[5]) }
    PREREAD_TO(pnN, (b + 2) * SPB)
    // chains for window b (register-only; overlaps with reads above)
    if (fwd) {
      FWD_STEP_BODY(0, eC, true);   // rescale once per window
      FWD_STEP_BODY(1, eC, false);
      FWD_STEP_BODY(2, eC, false);
      FWD_STEP_BODY(3, eC, false);
      FWD_STEP_BODY(4, eC, false);
      FWD_STEP_BODY(5, eC, false);
    } else {
      BWD_STEP_BODY(0, eC, true);
      BWD_STEP_BODY(1, eC, false);
      BWD_STEP_BODY(2, eC, false);
      BWD_STEP_BODY(3, eC, false);
      BWD_STEP_BODY(4, eC, false);
      BWD_STEP_BODY(5, eC, false);
    }
#pragma unroll
    for (int kk = 0; kk < 6; ++kk) { emit += emC[kk]; trn += trC[kk]; }
    ROTATE_NEXT
  }

  // ================= tail window 21 (2 steps; e/em/tr already in regs) ===
  {
    if (fwd) {
      FWD_STEP_BODY(0, eC, true);
      FWD_STEP_BODY(1, eC, false);
    } else {
      BWD_STEP_BODY(0, eC, true);
      BWD_STEP_BODY(1, eC, false);
    }
#pragma unroll
    for (int kk = 0; kk < 2; ++kk) { emit += emC[kk]; trn += trC[kk]; }
  }

  // ---- write partials (field-major)
  const int sq = seq0 + q;
  float* wp = ws + sq;
  if (fwd) {
    if (c < 3) {
#pragma unroll
      for (int k = 0; k < 3; ++k) wp[(3 * c + k) * B_N] = o[k];
    } else {
      wp[9 * B_N] = (float)ce;
      wp[10 * B_N] = emit + trn + initv[plr[0]];
    }
  } else {
    if (c < 3) {
#pragma unroll
      for (int k = 0; k < 3; ++k) wp[(11 + 3 * c + k) * B_N] = o[k];
    } else {
      wp[20 * B_N] = (float)ce;
      wp[21 * B_N] = emit + trn;
    }
  }
}

__global__ __launch_bounds__(256) void crf_combine(
    const float* __restrict__ ws, float* __restrict__ out)
{
  const int s = blockIdx.x * 256 + threadIdx.x;
  float dot = 0.f;
#pragma unroll
  for (int i = 0; i < 9; ++i)
    dot = fmaf(ws[i * B_N + s], ws[(11 + i) * B_N + s], dot);
  const float score =
      (__builtin_amdgcn_logf(dot) + ws[9 * B_N + s] + ws[20 * B_N + s]) * LN2f;
  out[s] = score - (ws[10 * B_N + s] + ws[21 * B_N + s]);
}

extern "C" void kernel_launch(void* const* d_in, const int* in_sizes, int n_in,
                              void* d_out, int out_size, void* d_ws, size_t ws_size,
                              hipStream_t stream) {
  (void)in_sizes; (void)n_in; (void)out_size; (void)ws_size;
  const float* xg    = (const float*)d_in[0];
  const int*   path  = (const int*)d_in[1];
  const float* tran  = (const float*)d_in[2];
  const float* initv = (const float*)d_in[3];
  float* ws  = (float*)d_ws;    // 22*8192*4 = 721 KB
  float* out = (float*)d_out;

  crf_half<<<2 * NDIR_BLOCKS, 64, 0, stream>>>(xg, path, tran, initv, ws);
  crf_combine<<<B_N / 256, 256, 0, stream>>>(ws, out);
}